// Round 16
// baseline (186.304 us; speedup 1.0000x reference)
//
#include <hip/hip_runtime.h>

#define EMBED 1024
#define NHEAD 16
#define HDIM  64
#define BATCH 2
#define SEQ   2048
#define MTOK  (BATCH * SEQ)   // 4096 tokens
#define QSCALE 0.1803368801f  // (1/sqrt(64)) * log2(e): softmax done in base 2

typedef __bf16 bf16x8 __attribute__((ext_vector_type(8)));
typedef float  f32x4  __attribute__((ext_vector_type(4)));

// round-half-up f32->bf16 (bias <= 2^-25, well under harness threshold)
__device__ __forceinline__ unsigned short f2bf(float f) {
  return (unsigned short)((__float_as_uint(f) + 0x8000u) >> 16);
}
// pack two f32 -> bf16x2 in one v_perm: low = bf(a), high = bf(b)
__device__ __forceinline__ unsigned int pkbf(float a, float b) {
  unsigned int ua = __float_as_uint(a) + 0x8000u;
  unsigned int ub = __float_as_uint(b) + 0x8000u;
  return __builtin_amdgcn_perm(ub, ua, 0x07060302u);
}

// async global->LDS, 16B/lane; LDS dest = wave-uniform base + lane*16
__device__ __forceinline__ void gload_lds16(const unsigned short* g, unsigned short* l) {
  __builtin_amdgcn_global_load_lds((__attribute__((address_space(1))) void*)g,
                                   (__attribute__((address_space(3))) void*)l, 16, 0, 0);
}

// key permutation for K staging: LDS row r holds key kperm(r) so that the QK
// output registers ARE the x32 PV A-fragment (keys quad*8..+7 per 32-block).
__device__ __forceinline__ int kperm(int r) {
  return (r & 32) | (((r >> 2) & 3) << 3) | (((r >> 4) & 1) << 2) | (r & 3);
}

// ---------------- prep: cast X -> bf16 (blocks 0..4095) + 4 weight transpose-casts ----------
__global__ __launch_bounds__(256)
void prep_k(const float* __restrict__ X, unsigned short* __restrict__ Xbf,
            const float* __restrict__ w0, const float* __restrict__ w1,
            const float* __restrict__ w2, const float* __restrict__ w3,
            unsigned short* __restrict__ t0, unsigned short* __restrict__ t1,
            unsigned short* __restrict__ t2, unsigned short* __restrict__ t3) {
  const int id = blockIdx.x;
  if (id < 4096) {                          // cast: 1M uint2 = 4M floats
    int i = id * 256 + threadIdx.x;
    float4 f = reinterpret_cast<const float4*>(X)[i];
    reinterpret_cast<uint2*>(Xbf)[i] = make_uint2(pkbf(f.x, f.y), pkbf(f.z, f.w));
    return;
  }
  const int t = id - 4096;                  // 0..1023: 4 weights x 256 tiles
  const float* s; unsigned short* d;
  switch (t >> 8) {
    case 0: s = w0; d = t0; break;
    case 1: s = w1; d = t1; break;
    case 2: s = w2; d = t2; break;
    default: s = w3; d = t3; break;
  }
  const int tt = t & 255;
  const int k0 = (tt >> 4) * 64, n0 = (tt & 15) * 64;
  __shared__ unsigned short T[64][65];
  for (int i = threadIdx.x; i < 4096; i += 256) {
    int r = i >> 6, c = i & 63;             // read coalesced over n
    T[c][r] = f2bf(s[(size_t)(k0 + r) * EMBED + n0 + c]);
  }
  __syncthreads();
  for (int i = threadIdx.x; i < 4096; i += 256) {
    int r = i >> 6, c = i & 63;             // write coalesced over k
    d[(size_t)(n0 + r) * EMBED + k0 + c] = T[r][c];
  }
}

// ---------------- GEMM  C[M][N] = A[M][1024] * Bt[N][1024]^T ----------------
// ROUND-0 VERBATIM (best-measured gemm config across 8 structural variants).
// BK=64, 2 barriers per K-tile, row-fastest grid, no launch_bounds.
template<int MODE, int BM>
__global__ void gemm_k(const unsigned short* __restrict__ A,
                       const unsigned short* __restrict__ Bt,
                       const float* __restrict__ b0, const float* __restrict__ b1,
                       const float* __restrict__ b2,
                       unsigned short* __restrict__ oQ, unsigned short* __restrict__ oK,
                       unsigned short* __restrict__ oV, float* __restrict__ oF) {
  constexpr int MI = BM / 32;
  __shared__ unsigned short As[BM][64];     // unpadded, XOR-swizzled 8-elem chunks
  __shared__ unsigned short Bs[128][64];
  const int tid = threadIdx.x, lane = tid & 63, wave = tid >> 6;
  const int lr = lane & 15, quad = lane >> 4;
  const int wm = (wave >> 1) * (BM / 2), wn = (wave & 1) * 64;
  const int row0 = blockIdx.x * BM, col0 = blockIdx.y * 128;   // row-fastest
  const int srow = lane >> 3, sc = lane & 7;
  const int sw0 = (quad ^ (lr & 7)) * 8;
  const int sw1 = ((quad ^ 4) ^ (lr & 7)) * 8;

  const f32x4 fz = {0.f, 0.f, 0.f, 0.f};
  f32x4 acc[MI][4];
#pragma unroll
  for (int i = 0; i < MI; ++i)
#pragma unroll
    for (int j = 0; j < 4; ++j) acc[i][j] = fz;

  for (int k0 = 0; k0 < EMBED; k0 += 64) {
#pragma unroll
    for (int g = 0; g < BM / 32; ++g) {
      int rbase = wave * (BM / 4) + g * 8;
      int row = rbase + srow;
      gload_lds16(&A[(size_t)(row0 + row) * EMBED + k0 + ((sc ^ (row & 7)) * 8)],
                  &As[rbase][0]);
    }
#pragma unroll
    for (int g = 0; g < 4; ++g) {
      int rbase = wave * 32 + g * 8;
      int row = rbase + srow;
      gload_lds16(&Bt[(size_t)(col0 + row) * EMBED + k0 + ((sc ^ (row & 7)) * 8)],
                  &Bs[rbase][0]);
    }
    __syncthreads();
#pragma unroll
    for (int kk = 0; kk < 64; kk += 32) {
      const int so = (kk == 0) ? sw0 : sw1;
      bf16x8 af[MI], bv[4];
#pragma unroll
      for (int i = 0; i < MI; ++i)
        af[i] = *reinterpret_cast<const bf16x8*>(&As[wm + i * 16 + lr][so]);
#pragma unroll
      for (int j = 0; j < 4; ++j)
        bv[j] = *reinterpret_cast<const bf16x8*>(&Bs[wn + j * 16 + lr][so]);
#pragma unroll
      for (int i = 0; i < MI; ++i)
#pragma unroll
        for (int j = 0; j < 4; ++j)
          acc[i][j] = __builtin_amdgcn_mfma_f32_16x16x32_bf16(af[i], bv[j],
                                                              acc[i][j], 0, 0, 0);
    }
    __syncthreads();
  }

#pragma unroll
  for (int i = 0; i < MI; ++i) {
#pragma unroll
    for (int j = 0; j < 4; ++j) {
      const int col = col0 + wn + j * 16 + lr;
      if (MODE == 1) {
        const float bb = b0[col];
#pragma unroll
        for (int r = 0; r < 4; ++r) {
          const int row = row0 + wm + i * 16 + quad * 4 + r;
          oF[((size_t)row << 10) + col] = acc[i][j][r] + bb;
        }
      } else {
        const int which = col >> 10, cn = col & 1023;   // wave-uniform
        const float bb = (which == 0 ? b0 : which == 1 ? b1 : b2)[cn];
        const float sscale = (which == 0) ? QSCALE : 1.0f;
        const int h = cn >> 6, dd = cn & 63;
#pragma unroll
        for (int r = 0; r < 4; ++r) {
          const int row = row0 + wm + i * 16 + quad * 4 + r;
          const int b = row >> 11, ss = row & (SEQ - 1);
          const float v = (acc[i][j][r] + bb) * sscale;
          if (which == 0) {
            oQ[((((size_t)b * NHEAD + h) * SEQ + ss) << 6) + dd] = f2bf(v);
          } else if (which == 1) {
            oK[((((size_t)b * NHEAD + h) * SEQ + ss) << 6) + dd] = f2bf(v);
          } else {
            oV[(((size_t)b * NHEAD + h) * HDIM + dd) * SEQ + ss] = f2bf(v);
          }
        }
      }
    }
  }
}

// ---------------- flash attention: QBLK=128, KVBLK=128, in-register P, MFMA-l ---------
// Round-16: R15 + l computed on the MATRIX pipe. lacc[g] = mfma(pf, ones, lacc)
// (8 extra MFMAs/wave/iter, +12.5% on a 28%-busy pipe) replaces 64 VALU adds
// per wave/iter AND the end-of-kernel shfl reduction: the MFMA C-layout
// (row = quad*4+r) delivers l[q] in exactly the per-lane slot the normalizer
// needs -> linv[r] = 1/lacc[g][r], no shuffles. Numerics: l now sums the SAME
// bf16 P used in the PV numerator (previously f32 exp2), making numerator and
// denominator consistent — softmax weights sum exactly to the denominator.
// absmax expected ~1-3.5e-3 (threshold 5.16e-3); this is the first round where
// the canary is EXPECTED to move at ulp level.
__global__ __launch_bounds__(256, 2)
void attn_k(const unsigned short* __restrict__ Qb,   // [B][H][S][Dh], pre-scaled
            const unsigned short* __restrict__ Kb,   // [B][H][S][Dh]
            const unsigned short* __restrict__ Vt,   // [B][H][Dh][S]
            unsigned short* __restrict__ Ctx) {      // [B][S][EMBED] bf16
  __shared__ unsigned short Ks[2][2][64][64];   // [buf][half][row][k] key-permuted
  __shared__ unsigned short Vs[2][2][64][64];   // [buf][half][dh][key]
  const int tid = threadIdx.x, lane = tid & 63, wave = tid >> 6;
  const int lr = lane & 15, quad = lane >> 4;
  const int bh = blockIdx.x, qt = blockIdx.y;
  const size_t base = (size_t)bh * SEQ * HDIM;
  const int srow = lane >> 3, sc = lane & 7;
  const int sw0 = (quad ^ (lr & 7)) * 8;
  const int sw1 = ((quad ^ 4) ^ (lr & 7)) * 8;
  constexpr int NT = SEQ / 128;             // 16 iterations of 128 keys

  // ones B-frag for the l matvec (bf16 1.0 = 0x3F80 in all 8 slots)
  union { unsigned int u[4]; bf16x8 v; } onesu;
  onesu.u[0] = 0x3F803F80u; onesu.u[1] = 0x3F803F80u;
  onesu.u[2] = 0x3F803F80u; onesu.u[3] = 0x3F803F80u;
  const bf16x8 onesv = onesu.v;

  // Q frags direct from global (B operand: n = q = lane&15) — R6/R11-proven
  bf16x8 qf[2][2];
#pragma unroll
  for (int g = 0; g < 2; ++g) {
    const unsigned short* qrow =
        &Qb[base + (size_t)(qt * 128 + wave * 32 + g * 16 + lr) * HDIM];
    qf[g][0] = *reinterpret_cast<const bf16x8*>(&qrow[quad * 8]);
    qf[g][1] = *reinterpret_cast<const bf16x8*>(&qrow[(quad ^ 4) * 8]);
  }

  // stage one 128-key tile (both halves) into buffer bufi; 8 gloads/wave
  auto stage = [&](int bufi, int kt) {
#pragma unroll
    for (int h = 0; h < 2; ++h)
#pragma unroll
      for (int g = 0; g < 2; ++g) {
        int rbase = wave * 16 + g * 8;
        int row = rbase + srow;
        gload_lds16(&Kb[base + (size_t)(kt * 128 + h * 64 + kperm(row)) * HDIM +
                        ((sc ^ (row & 7)) * 8)],
                    &Ks[bufi][h][rbase][0]);
        gload_lds16(&Vt[base + (size_t)row * SEQ + kt * 128 + h * 64 +
                        ((sc ^ (row & 7)) * 8)],
                    &Vs[bufi][h][rbase][0]);
      }
  };

  stage(0, 0);
  __syncthreads();

  const f32x4 fz = {0.f, 0.f, 0.f, 0.f};
  f32x4 oacc[2][4];
  f32x4 lacc[2] = {fz, fz};                 // l[q] accumulated on the MFMA pipe
#pragma unroll
  for (int g = 0; g < 2; ++g)
#pragma unroll
    for (int d = 0; d < 4; ++d) oacc[g][d] = fz;

  for (int kt = 0;;) {
    const int buf = kt & 1;

    // issue async prefetch of the NEXT 128-key tile BEFORE compute; the
    // end-of-iter barrier's vmcnt drain overlaps the whole (doubled) compute.
    if (kt + 1 < NT) stage(buf ^ 1, kt + 1);

    // two 64-key halves, processed exactly like two R8 iterations
#pragma unroll
    for (int h = 0; h < 2; ++h) {
      // S^T[key][q]: A = permuted K rows, B = Q
      f32x4 sc4[2][4];
#pragma unroll
      for (int nt = 0; nt < 4; ++nt) {
        bf16x8 kf0 = *reinterpret_cast<const bf16x8*>(&Ks[buf][h][nt * 16 + lr][sw0]);
        bf16x8 kf1 = *reinterpret_cast<const bf16x8*>(&Ks[buf][h][nt * 16 + lr][sw1]);
#pragma unroll
        for (int g = 0; g < 2; ++g) {
          f32x4 a = __builtin_amdgcn_mfma_f32_16x16x32_bf16(kf0, qf[g][0], fz, 0, 0, 0);
          sc4[g][nt] = __builtin_amdgcn_mfma_f32_16x16x32_bf16(kf1, qf[g][1], a, 0, 0, 0);
        }
      }

      // P = exp2(S); pack in-register as x32 A-frags (no scalar l adds)
      bf16x8 pf[2][2];
#pragma unroll
      for (int g = 0; g < 2; ++g)
#pragma unroll
        for (int b = 0; b < 2; ++b) {
          float e0 = __builtin_amdgcn_exp2f(sc4[g][2 * b][0]);
          float e1 = __builtin_amdgcn_exp2f(sc4[g][2 * b][1]);
          float e2 = __builtin_amdgcn_exp2f(sc4[g][2 * b][2]);
          float e3 = __builtin_amdgcn_exp2f(sc4[g][2 * b][3]);
          float o0 = __builtin_amdgcn_exp2f(sc4[g][2 * b + 1][0]);
          float o1 = __builtin_amdgcn_exp2f(sc4[g][2 * b + 1][1]);
          float o2 = __builtin_amdgcn_exp2f(sc4[g][2 * b + 1][2]);
          float o3 = __builtin_amdgcn_exp2f(sc4[g][2 * b + 1][3]);
          union { unsigned int u[4]; bf16x8 v; } pk;
          pk.u[0] = pkbf(e0, e1);
          pk.u[1] = pkbf(e2, e3);
          pk.u[2] = pkbf(o0, o1);
          pk.u[3] = pkbf(o2, o3);
          pf[g][b] = pk.v;
        }

      // l[q] += P x ones (matrix pipe); C-layout row = quad*4+r == the exact
      // per-lane slot the normalizer needs.
#pragma unroll
      for (int g = 0; g < 2; ++g) {
        lacc[g] = __builtin_amdgcn_mfma_f32_16x16x32_bf16(pf[g][0], onesv, lacc[g], 0, 0, 0);
        lacc[g] = __builtin_amdgcn_mfma_f32_16x16x32_bf16(pf[g][1], onesv, lacc[g], 0, 0, 0);
      }

      // PV: O[q][dh] += P x V (P from registers)
#pragma unroll
      for (int d = 0; d < 4; ++d) {
        bf16x8 vb0 = *reinterpret_cast<const bf16x8*>(&Vs[buf][h][d * 16 + lr][sw0]);
        bf16x8 vb1 = *reinterpret_cast<const bf16x8*>(&Vs[buf][h][d * 16 + lr][sw1]);
#pragma unroll
        for (int g = 0; g < 2; ++g) {
          oacc[g][d] = __builtin_amdgcn_mfma_f32_16x16x32_bf16(pf[g][0], vb0, oacc[g][d], 0, 0, 0);
          oacc[g][d] = __builtin_amdgcn_mfma_f32_16x16x32_bf16(pf[g][1], vb1, oacc[g][d], 0, 0, 0);
        }
      }
    }

    if (++kt == NT) break;
    // single barrier per 128 keys: (a) all waves done reading buf; (b) drains
    // prefetch vmcnt -> buf^1 fully staged for next iter.
    __syncthreads();
  }

  // finalize: l already lives per-lane in lacc[g][r] — no shuffles needed.
  const int b = bh >> 4, h = bh & 15;
#pragma unroll
  for (int g = 0; g < 2; ++g) {
    float linv[4];
#pragma unroll
    for (int r = 0; r < 4; ++r) linv[r] = 1.0f / lacc[g][r];
#pragma unroll
    for (int d = 0; d < 4; ++d)
#pragma unroll
      for (int r = 0; r < 4; ++r) {
        const int q = qt * 128 + wave * 32 + g * 16 + quad * 4 + r;
        Ctx[(((size_t)b * SEQ + q) << 10) + h * 64 + d * 16 + lr] =
            f2bf(oacc[g][d][r] * linv[r]);
      }
  }
}

// ---------------- launch ----------------
extern "C" void kernel_launch(void* const* d_in, const int* in_sizes, int n_in,
                              void* d_out, int out_size, void* d_ws, size_t ws_size,
                              hipStream_t stream) {
  const float* X  = (const float*)d_in[0];
  const float* Wq = (const float*)d_in[1];
  const float* bq = (const float*)d_in[2];
  const float* Wk = (const float*)d_in[3];
  const float* bk = (const float*)d_in[4];
  const float* Wv = (const float*)d_in[5];
  const float* bv = (const float*)d_in[6];
  const float* Wo = (const float*)d_in[7];
  const float* bo = (const float*)d_in[8];

  unsigned short* ws = (unsigned short*)d_ws;
  const size_t M1 = (size_t)1024 * 1024;
  unsigned short* Xbf = ws;                 // 4M shorts
  unsigned short* WqT = ws + 4 * M1;        // weights n-major (q,k,v contiguous for fused B)
  unsigned short* WkT = ws + 5 * M1;
  unsigned short* WvT = ws + 6 * M1;
  unsigned short* WoT = ws + 7 * M1;
  unsigned short* Qb  = ws + 8 * M1;
  unsigned short* Kb  = ws + 12 * M1;
  unsigned short* Vt  = ws + 16 * M1;
  unsigned short* Ctx = ws + 20 * M1;       // 48 MB total

  // prep: cast X (4096 blocks) + 4 weight transposes (1024 blocks)
  prep_k<<<5120, 256, 0, stream>>>(X, Xbf, Wq, Wk, Wv, Wo, WqT, WkT, WvT, WoT);

  // fused QKV projection: Bt = [WqT;WkT;WvT], N=3072; R0-verbatim BK=64 2-barrier
  gemm_k<0, 128><<<dim3(MTOK / 128, 3072 / 128), 256, 0, stream>>>(
      Xbf, WqT, bq, bk, bv, Qb, Kb, Vt, nullptr);

  // grid x = bh for XCD-pinned K/V L2 residency; QBLK=128, KVBLK=128, MFMA-l
  attn_k<<<dim3(BATCH * NHEAD, SEQ / 128), 256, 0, stream>>>(Qb, Kb, Vt, Ctx);

  // output projection: R0-verbatim 64x128 BK=64 2-barrier
  gemm_k<1, 64><<<dim3(MTOK / 64, EMBED / 128), 256, 0, stream>>>(
      Ctx, WoT, bo, nullptr, nullptr, nullptr, nullptr, nullptr, (float*)d_out);
}

// Round 17
// 179.506 us; speedup vs baseline: 1.0379x; 1.0379x over previous
//
#include <hip/hip_runtime.h>

#define EMBED 1024
#define NHEAD 16
#define HDIM  64
#define BATCH 2
#define SEQ   2048
#define MTOK  (BATCH * SEQ)   // 4096 tokens
#define QSCALE 0.1803368801f  // (1/sqrt(64)) * log2(e): softmax done in base 2

typedef __bf16 bf16x8 __attribute__((ext_vector_type(8)));
typedef float  f32x4  __attribute__((ext_vector_type(4)));

// round-half-up f32->bf16 (bias <= 2^-25, well under harness threshold)
__device__ __forceinline__ unsigned short f2bf(float f) {
  return (unsigned short)((__float_as_uint(f) + 0x8000u) >> 16);
}
// pack two f32 -> bf16x2 in one v_perm: low = bf(a), high = bf(b)
__device__ __forceinline__ unsigned int pkbf(float a, float b) {
  unsigned int ua = __float_as_uint(a) + 0x8000u;
  unsigned int ub = __float_as_uint(b) + 0x8000u;
  return __builtin_amdgcn_perm(ub, ua, 0x07060302u);
}

// async global->LDS, 16B/lane; LDS dest = wave-uniform base + lane*16
__device__ __forceinline__ void gload_lds16(const unsigned short* g, unsigned short* l) {
  __builtin_amdgcn_global_load_lds((__attribute__((address_space(1))) void*)g,
                                   (__attribute__((address_space(3))) void*)l, 16, 0, 0);
}

// key permutation for K staging: LDS row r holds key kperm(r) so that the QK
// output registers ARE the x32 PV A-fragment (keys quad*8..+7 per 32-block).
__device__ __forceinline__ int kperm(int r) {
  return (r & 32) | (((r >> 2) & 3) << 3) | (((r >> 4) & 1) << 2) | (r & 3);
}

// ---------------- prep: cast X -> bf16 (blocks 0..4095) + 4 weight transpose-casts ----------
__global__ __launch_bounds__(256)
void prep_k(const float* __restrict__ X, unsigned short* __restrict__ Xbf,
            const float* __restrict__ w0, const float* __restrict__ w1,
            const float* __restrict__ w2, const float* __restrict__ w3,
            unsigned short* __restrict__ t0, unsigned short* __restrict__ t1,
            unsigned short* __restrict__ t2, unsigned short* __restrict__ t3) {
  const int id = blockIdx.x;
  if (id < 4096) {                          // cast: 1M uint2 = 4M floats
    int i = id * 256 + threadIdx.x;
    float4 f = reinterpret_cast<const float4*>(X)[i];
    reinterpret_cast<uint2*>(Xbf)[i] = make_uint2(pkbf(f.x, f.y), pkbf(f.z, f.w));
    return;
  }
  const int t = id - 4096;                  // 0..1023: 4 weights x 256 tiles
  const float* s; unsigned short* d;
  switch (t >> 8) {
    case 0: s = w0; d = t0; break;
    case 1: s = w1; d = t1; break;
    case 2: s = w2; d = t2; break;
    default: s = w3; d = t3; break;
  }
  const int tt = t & 255;
  const int k0 = (tt >> 4) * 64, n0 = (tt & 15) * 64;
  __shared__ unsigned short T[64][65];
  for (int i = threadIdx.x; i < 4096; i += 256) {
    int r = i >> 6, c = i & 63;             // read coalesced over n
    T[c][r] = f2bf(s[(size_t)(k0 + r) * EMBED + n0 + c]);
  }
  __syncthreads();
  for (int i = threadIdx.x; i < 4096; i += 256) {
    int r = i >> 6, c = i & 63;             // write coalesced over k
    d[(size_t)(n0 + r) * EMBED + k0 + c] = T[r][c];
  }
}

// ---------------- GEMM  C[M][N] = A[M][1024] * Bt[N][1024]^T ----------------
// ROUND-0 VERBATIM (best-measured gemm config across 9 structural variants).
// BK=64, 2 barriers per K-tile, row-fastest grid, no launch_bounds.
template<int MODE, int BM>
__global__ void gemm_k(const unsigned short* __restrict__ A,
                       const unsigned short* __restrict__ Bt,
                       const float* __restrict__ b0, const float* __restrict__ b1,
                       const float* __restrict__ b2,
                       unsigned short* __restrict__ oQ, unsigned short* __restrict__ oK,
                       unsigned short* __restrict__ oV, float* __restrict__ oF) {
  constexpr int MI = BM / 32;
  __shared__ unsigned short As[BM][64];     // unpadded, XOR-swizzled 8-elem chunks
  __shared__ unsigned short Bs[128][64];
  const int tid = threadIdx.x, lane = tid & 63, wave = tid >> 6;
  const int lr = lane & 15, quad = lane >> 4;
  const int wm = (wave >> 1) * (BM / 2), wn = (wave & 1) * 64;
  const int row0 = blockIdx.x * BM, col0 = blockIdx.y * 128;   // row-fastest
  const int srow = lane >> 3, sc = lane & 7;
  const int sw0 = (quad ^ (lr & 7)) * 8;
  const int sw1 = ((quad ^ 4) ^ (lr & 7)) * 8;

  const f32x4 fz = {0.f, 0.f, 0.f, 0.f};
  f32x4 acc[MI][4];
#pragma unroll
  for (int i = 0; i < MI; ++i)
#pragma unroll
    for (int j = 0; j < 4; ++j) acc[i][j] = fz;

  for (int k0 = 0; k0 < EMBED; k0 += 64) {
#pragma unroll
    for (int g = 0; g < BM / 32; ++g) {
      int rbase = wave * (BM / 4) + g * 8;
      int row = rbase + srow;
      gload_lds16(&A[(size_t)(row0 + row) * EMBED + k0 + ((sc ^ (row & 7)) * 8)],
                  &As[rbase][0]);
    }
#pragma unroll
    for (int g = 0; g < 4; ++g) {
      int rbase = wave * 32 + g * 8;
      int row = rbase + srow;
      gload_lds16(&Bt[(size_t)(col0 + row) * EMBED + k0 + ((sc ^ (row & 7)) * 8)],
                  &Bs[rbase][0]);
    }
    __syncthreads();
#pragma unroll
    for (int kk = 0; kk < 64; kk += 32) {
      const int so = (kk == 0) ? sw0 : sw1;
      bf16x8 af[MI], bv[4];
#pragma unroll
      for (int i = 0; i < MI; ++i)
        af[i] = *reinterpret_cast<const bf16x8*>(&As[wm + i * 16 + lr][so]);
#pragma unroll
      for (int j = 0; j < 4; ++j)
        bv[j] = *reinterpret_cast<const bf16x8*>(&Bs[wn + j * 16 + lr][so]);
#pragma unroll
      for (int i = 0; i < MI; ++i)
#pragma unroll
        for (int j = 0; j < 4; ++j)
          acc[i][j] = __builtin_amdgcn_mfma_f32_16x16x32_bf16(af[i], bv[j],
                                                              acc[i][j], 0, 0, 0);
    }
    __syncthreads();
  }

#pragma unroll
  for (int i = 0; i < MI; ++i) {
#pragma unroll
    for (int j = 0; j < 4; ++j) {
      const int col = col0 + wn + j * 16 + lr;
      if (MODE == 1) {
        const float bb = b0[col];
#pragma unroll
        for (int r = 0; r < 4; ++r) {
          const int row = row0 + wm + i * 16 + quad * 4 + r;
          oF[((size_t)row << 10) + col] = acc[i][j][r] + bb;
        }
      } else {
        const int which = col >> 10, cn = col & 1023;   // wave-uniform
        const float bb = (which == 0 ? b0 : which == 1 ? b1 : b2)[cn];
        const float sscale = (which == 0) ? QSCALE : 1.0f;
        const int h = cn >> 6, dd = cn & 63;
#pragma unroll
        for (int r = 0; r < 4; ++r) {
          const int row = row0 + wm + i * 16 + quad * 4 + r;
          const int b = row >> 11, ss = row & (SEQ - 1);
          const float v = (acc[i][j][r] + bb) * sscale;
          if (which == 0) {
            oQ[((((size_t)b * NHEAD + h) * SEQ + ss) << 6) + dd] = f2bf(v);
          } else if (which == 1) {
            oK[((((size_t)b * NHEAD + h) * SEQ + ss) << 6) + dd] = f2bf(v);
          } else {
            oV[(((size_t)b * NHEAD + h) * HDIM + dd) * SEQ + ss] = f2bf(v);
          }
        }
      }
    }
  }
}

// ---------------- flash attention: QBLK=128, KVBLK=128, in-register P, MFMA-l ---------
// (round-16 verbatim — best-measured attn: 45.0 us, MfmaUtil 33.8, VALU 40.5,
// conflicts 0. l computed on the matrix pipe via mfma(P, ones, lacc); C-layout
// row=quad*4+r delivers l[q] in the exact per-lane slot the normalizer needs.)
__global__ __launch_bounds__(256, 2)
void attn_k(const unsigned short* __restrict__ Qb,   // [B][H][S][Dh], pre-scaled
            const unsigned short* __restrict__ Kb,   // [B][H][S][Dh]
            const unsigned short* __restrict__ Vt,   // [B][H][Dh][S]
            unsigned short* __restrict__ Ctx) {      // [B][S][EMBED] bf16
  __shared__ unsigned short Ks[2][2][64][64];   // [buf][half][row][k] key-permuted
  __shared__ unsigned short Vs[2][2][64][64];   // [buf][half][dh][key]
  const int tid = threadIdx.x, lane = tid & 63, wave = tid >> 6;
  const int lr = lane & 15, quad = lane >> 4;
  const int bh = blockIdx.x, qt = blockIdx.y;
  const size_t base = (size_t)bh * SEQ * HDIM;
  const int srow = lane >> 3, sc = lane & 7;
  const int sw0 = (quad ^ (lr & 7)) * 8;
  const int sw1 = ((quad ^ 4) ^ (lr & 7)) * 8;
  constexpr int NT = SEQ / 128;             // 16 iterations of 128 keys

  // ones B-frag for the l matvec (bf16 1.0 = 0x3F80 in all 8 slots)
  union { unsigned int u[4]; bf16x8 v; } onesu;
  onesu.u[0] = 0x3F803F80u; onesu.u[1] = 0x3F803F80u;
  onesu.u[2] = 0x3F803F80u; onesu.u[3] = 0x3F803F80u;
  const bf16x8 onesv = onesu.v;

  // Q frags direct from global (B operand: n = q = lane&15) — R6/R11-proven
  bf16x8 qf[2][2];
#pragma unroll
  for (int g = 0; g < 2; ++g) {
    const unsigned short* qrow =
        &Qb[base + (size_t)(qt * 128 + wave * 32 + g * 16 + lr) * HDIM];
    qf[g][0] = *reinterpret_cast<const bf16x8*>(&qrow[quad * 8]);
    qf[g][1] = *reinterpret_cast<const bf16x8*>(&qrow[(quad ^ 4) * 8]);
  }

  // stage one 128-key tile (both halves) into buffer bufi; 8 gloads/wave
  auto stage = [&](int bufi, int kt) {
#pragma unroll
    for (int h = 0; h < 2; ++h)
#pragma unroll
      for (int g = 0; g < 2; ++g) {
        int rbase = wave * 16 + g * 8;
        int row = rbase + srow;
        gload_lds16(&Kb[base + (size_t)(kt * 128 + h * 64 + kperm(row)) * HDIM +
                        ((sc ^ (row & 7)) * 8)],
                    &Ks[bufi][h][rbase][0]);
        gload_lds16(&Vt[base + (size_t)row * SEQ + kt * 128 + h * 64 +
                        ((sc ^ (row & 7)) * 8)],
                    &Vs[bufi][h][rbase][0]);
      }
  };

  stage(0, 0);
  __syncthreads();

  const f32x4 fz = {0.f, 0.f, 0.f, 0.f};
  f32x4 oacc[2][4];
  f32x4 lacc[2] = {fz, fz};                 // l[q] accumulated on the MFMA pipe
#pragma unroll
  for (int g = 0; g < 2; ++g)
#pragma unroll
    for (int d = 0; d < 4; ++d) oacc[g][d] = fz;

  for (int kt = 0;;) {
    const int buf = kt & 1;

    // issue async prefetch of the NEXT 128-key tile BEFORE compute; the
    // end-of-iter barrier's vmcnt drain overlaps the whole (doubled) compute.
    if (kt + 1 < NT) stage(buf ^ 1, kt + 1);

    // two 64-key halves, processed exactly like two R8 iterations
#pragma unroll
    for (int h = 0; h < 2; ++h) {
      // S^T[key][q]: A = permuted K rows, B = Q
      f32x4 sc4[2][4];
#pragma unroll
      for (int nt = 0; nt < 4; ++nt) {
        bf16x8 kf0 = *reinterpret_cast<const bf16x8*>(&Ks[buf][h][nt * 16 + lr][sw0]);
        bf16x8 kf1 = *reinterpret_cast<const bf16x8*>(&Ks[buf][h][nt * 16 + lr][sw1]);
#pragma unroll
        for (int g = 0; g < 2; ++g) {
          f32x4 a = __builtin_amdgcn_mfma_f32_16x16x32_bf16(kf0, qf[g][0], fz, 0, 0, 0);
          sc4[g][nt] = __builtin_amdgcn_mfma_f32_16x16x32_bf16(kf1, qf[g][1], a, 0, 0, 0);
        }
      }

      // P = exp2(S); pack in-register as x32 A-frags (no scalar l adds)
      bf16x8 pf[2][2];
#pragma unroll
      for (int g = 0; g < 2; ++g)
#pragma unroll
        for (int b = 0; b < 2; ++b) {
          float e0 = __builtin_amdgcn_exp2f(sc4[g][2 * b][0]);
          float e1 = __builtin_amdgcn_exp2f(sc4[g][2 * b][1]);
          float e2 = __builtin_amdgcn_exp2f(sc4[g][2 * b][2]);
          float e3 = __builtin_amdgcn_exp2f(sc4[g][2 * b][3]);
          float o0 = __builtin_amdgcn_exp2f(sc4[g][2 * b + 1][0]);
          float o1 = __builtin_amdgcn_exp2f(sc4[g][2 * b + 1][1]);
          float o2 = __builtin_amdgcn_exp2f(sc4[g][2 * b + 1][2]);
          float o3 = __builtin_amdgcn_exp2f(sc4[g][2 * b + 1][3]);
          union { unsigned int u[4]; bf16x8 v; } pk;
          pk.u[0] = pkbf(e0, e1);
          pk.u[1] = pkbf(e2, e3);
          pk.u[2] = pkbf(o0, o1);
          pk.u[3] = pkbf(o2, o3);
          pf[g][b] = pk.v;
        }

      // l[q] += P x ones (matrix pipe); C-layout row = quad*4+r == the exact
      // per-lane slot the normalizer needs.
#pragma unroll
      for (int g = 0; g < 2; ++g) {
        lacc[g] = __builtin_amdgcn_mfma_f32_16x16x32_bf16(pf[g][0], onesv, lacc[g], 0, 0, 0);
        lacc[g] = __builtin_amdgcn_mfma_f32_16x16x32_bf16(pf[g][1], onesv, lacc[g], 0, 0, 0);
      }

      // PV: O[q][dh] += P x V (P from registers)
#pragma unroll
      for (int d = 0; d < 4; ++d) {
        bf16x8 vb0 = *reinterpret_cast<const bf16x8*>(&Vs[buf][h][d * 16 + lr][sw0]);
        bf16x8 vb1 = *reinterpret_cast<const bf16x8*>(&Vs[buf][h][d * 16 + lr][sw1]);
#pragma unroll
        for (int g = 0; g < 2; ++g) {
          oacc[g][d] = __builtin_amdgcn_mfma_f32_16x16x32_bf16(pf[g][0], vb0, oacc[g][d], 0, 0, 0);
          oacc[g][d] = __builtin_amdgcn_mfma_f32_16x16x32_bf16(pf[g][1], vb1, oacc[g][d], 0, 0, 0);
        }
      }
    }

    if (++kt == NT) break;
    // single barrier per 128 keys: (a) all waves done reading buf; (b) drains
    // prefetch vmcnt -> buf^1 fully staged for next iter.
    __syncthreads();
  }

  // finalize: l already lives per-lane in lacc[g][r] — no shuffles needed.
  const int b = bh >> 4, h = bh & 15;
#pragma unroll
  for (int g = 0; g < 2; ++g) {
    float linv[4];
#pragma unroll
    for (int r = 0; r < 4; ++r) linv[r] = 1.0f / lacc[g][r];
#pragma unroll
    for (int d = 0; d < 4; ++d)
#pragma unroll
      for (int r = 0; r < 4; ++r) {
        const int q = qt * 128 + wave * 32 + g * 16 + quad * 4 + r;
        Ctx[(((size_t)b * SEQ + q) << 10) + h * 64 + d * 16 + lr] =
            f2bf(oacc[g][d][r] * linv[r]);
      }
  }
}

// ---------------- launch ----------------
extern "C" void kernel_launch(void* const* d_in, const int* in_sizes, int n_in,
                              void* d_out, int out_size, void* d_ws, size_t ws_size,
                              hipStream_t stream) {
  const float* X  = (const float*)d_in[0];
  const float* Wq = (const float*)d_in[1];
  const float* bq = (const float*)d_in[2];
  const float* Wk = (const float*)d_in[3];
  const float* bk = (const float*)d_in[4];
  const float* Wv = (const float*)d_in[5];
  const float* bv = (const float*)d_in[6];
  const float* Wo = (const float*)d_in[7];
  const float* bo = (const float*)d_in[8];

  unsigned short* ws = (unsigned short*)d_ws;
  const size_t M1 = (size_t)1024 * 1024;
  unsigned short* Xbf = ws;                 // 4M shorts
  unsigned short* WqT = ws + 4 * M1;        // weights n-major (q,k,v contiguous for fused B)
  unsigned short* WkT = ws + 5 * M1;
  unsigned short* WvT = ws + 6 * M1;
  unsigned short* WoT = ws + 7 * M1;
  unsigned short* Qb  = ws + 8 * M1;
  unsigned short* Kb  = ws + 12 * M1;
  unsigned short* Vt  = ws + 16 * M1;
  unsigned short* Ctx = ws + 20 * M1;       // 48 MB total

  // prep: cast X (4096 blocks) + 4 weight transposes (1024 blocks)
  prep_k<<<5120, 256, 0, stream>>>(X, Xbf, Wq, Wk, Wv, Wo, WqT, WkT, WvT, WoT);

  // fused QKV projection: Bt = [WqT;WkT;WvT], N=3072; R0-verbatim BK=64 2-barrier
  gemm_k<0, 128><<<dim3(MTOK / 128, 3072 / 128), 256, 0, stream>>>(
      Xbf, WqT, bq, bk, bv, Qb, Kb, Vt, nullptr);

  // grid x = bh for XCD-pinned K/V L2 residency; QBLK=128, KVBLK=128, MFMA-l
  attn_k<<<dim3(BATCH * NHEAD, SEQ / 128), 256, 0, stream>>>(Qb, Kb, Vt, Ctx);

  // output projection: R0-verbatim 64x128 BK=64 2-barrier
  gemm_k<1, 64><<<dim3(MTOK / 64, EMBED / 128), 256, 0, stream>>>(
      Ctx, WoT, bo, nullptr, nullptr, nullptr, nullptr, nullptr, (float*)d_out);
}